// Round 1
// baseline (117.846 us; speedup 1.0000x reference)
//
#include <hip/hip_runtime.h>
#include <math.h>

namespace {

constexpr int kN       = 4096;            // points / queries per batch
constexpr int kThreads = 256;             // threads per block
constexpr int kEPT     = kN / kThreads;   // 16 elements per thread
constexpr int kIters   = 18;              // bisection iterations: delta = 16/2^18 ~ 6e-5
constexpr float kM0    = 0.3f;

__device__ __forceinline__ float waveReduceSum(float v) {
#pragma unroll
    for (int off = 32; off >= 1; off >>= 1)
        v += __shfl_xor(v, off);
    return v;
}

__global__ __launch_bounds__(kThreads, 4)
void dtm_kernel(const float* __restrict__ input,   // (B, N, 2)
                const float* __restrict__ weight,  // (B, N)
                const float* __restrict__ grid,    // (N, 2)
                float* __restrict__ out,           // (B, N)
                int nq) {
    const int q = blockIdx.x;
    if (q >= nq) return;
    const int b = q >> 12;          // q / 4096
    const int i = q & (kN - 1);     // q % 4096

    // Query point (uniform across block -> scalar loads)
    const float gx = grid[2 * i];
    const float gy = grid[2 * i + 1];
    const float2* inp = (const float2*)input + (size_t)b * kN;
    const float*  wgt = weight + (size_t)b * kN;

    const int t = threadIdx.x;

    // Compute squared distances once; keep (d2, w) in registers for all passes.
    float d2[kEPT], w[kEPT];
    float wloc = 0.f;
#pragma unroll
    for (int s = 0; s < kEPT; ++s) {
        const int j = t + s * kThreads;     // coalesced across lanes
        const float2 p = inp[j];
        const float dx = gx - p.x;
        const float dy = gy - p.y;
        d2[s] = dx * dx + dy * dy;
        const float wj = wgt[j];
        w[s] = wj;
        wloc += wj;
    }

    __shared__ float part[2][4];   // parity-double-buffered cross-wave partials
    __shared__ float fin[2][4];    // final (W, A) partials

    const int wave = t >> 6;
    const bool leader = (t & 63) == 0;

    // Total weight -> weight bound wb = M0 * sum(w).
    // Uses slot parity 1; iteration 0 uses slot 0, so one barrier suffices.
    {
        const float wv = waveReduceSum(wloc);
        if (leader) part[1][wave] = wv;
    }
    __syncthreads();
    const float total = part[1][0] + part[1][1] + part[1][2] + part[1][3];
    const float wb = kM0 * total;

    // Bisection on the d2 threshold.
    // Invariant: T(lo) < wb <= T(hi), where T(t) = sum of w over d2 <= t.
    // (T(0)=0 < wb; T(16) = total >= wb since all |coord| <= ~1.3.)
    float lo = 0.f, hi = 16.f;
    for (int it = 0; it < kIters; ++it) {
        const float mid = 0.5f * (lo + hi);
        float local = 0.f;
#pragma unroll
        for (int s = 0; s < kEPT; ++s)
            local += (d2[s] <= mid) ? w[s] : 0.f;
        const float pv = waveReduceSum(local);
        if (leader) part[it & 1][wave] = pv;
        __syncthreads();
        const float* pp = part[it & 1];
        const float T = pp[0] + pp[1] + pp[2] + pp[3];   // identical on all threads -> uniform branch
        if (T >= wb) hi = mid; else lo = mid;
    }

    // Exact sums below lo (T(lo) < wb guaranteed); mass in (lo, hi] priced at hi.
    // True threshold d2* is in (lo, hi], so error <= (hi-lo) * wb on dtm.
    float lw = 0.f, la = 0.f;
#pragma unroll
    for (int s = 0; s < kEPT; ++s) {
        const bool c = d2[s] <= lo;
        lw += c ? w[s] : 0.f;
        la += c ? d2[s] * w[s] : 0.f;
    }
    const float rw = waveReduceSum(lw);
    const float ra = waveReduceSum(la);
    if (leader) { fin[0][wave] = rw; fin[1][wave] = ra; }
    __syncthreads();
    if (t == 0) {
        const float W = fin[0][0] + fin[0][1] + fin[0][2] + fin[0][3];
        const float A = fin[1][0] + fin[1][1] + fin[1][2] + fin[1][3];
        const float dtm = A + hi * (wb - W);
        out[q] = sqrtf(dtm / wb);
    }
}

}  // namespace

extern "C" void kernel_launch(void* const* d_in, const int* in_sizes, int n_in,
                              void* d_out, int out_size, void* d_ws, size_t ws_size,
                              hipStream_t stream) {
    const float* input  = (const float*)d_in[0];   // (B, N, 2) f32
    const float* weight = (const float*)d_in[1];   // (B, N)    f32
    const float* grid   = (const float*)d_in[2];   // (N, 2)    f32
    float* out = (float*)d_out;                    // (B, N)    f32
    const int nq = out_size;                       // B * N = 8192
    dtm_kernel<<<dim3(nq), dim3(kThreads), 0, stream>>>(input, weight, grid, out, nq);
}